// Round 1
// baseline (4493.981 us; speedup 1.0000x reference)
//
#include <hip/hip_runtime.h>
#include <math.h>

#define HS 524288
#define HSM (HS - 1)
#define ENC_NEGINF 0x007FFFFFu

__device__ __forceinline__ unsigned encf(float f) {
    unsigned b = __float_as_uint(f);
    return (b & 0x80000000u) ? ~b : (b | 0x80000000u);
}
__device__ __forceinline__ float decf(unsigned u) {
    return __uint_as_float((u & 0x80000000u) ? (u & 0x7FFFFFFFu) : ~u);
}

// ---------------------------------------------------------------- setup kernels

__global__ __launch_bounds__(256) void k_init_static(unsigned* hashK, int* hashV,
                                                     int* rowcnt, int* colcnt, int N) {
    int i = blockIdx.x * 256 + threadIdx.x;
    if (i < HS) { hashK[i] = 0xFFFFFFFFu; hashV[i] = 0x7FFFFFFF; }
    if (i < N) { rowcnt[i] = 0; colcnt[i] = 0; }
}

__global__ __launch_bounds__(256) void k_hash_insert(const int* __restrict__ row,
                                                     const int* __restrict__ col,
                                                     unsigned* hashK, int* hashV, int N, int E) {
    int e = blockIdx.x * 256 + threadIdx.x;
    if (e >= E) return;
    unsigned key = (unsigned)row[e] * (unsigned)N + (unsigned)col[e];
    unsigned h = (key * 2654435761u) >> 13; h &= HSM;
    while (true) {
        unsigned prev = atomicCAS(&hashK[h], 0xFFFFFFFFu, key);
        if (prev == 0xFFFFFFFFu || prev == key) { atomicMin(&hashV[h], e); break; }
        h = (h + 1) & HSM;
    }
}

__global__ __launch_bounds__(256) void k_hash_lookup(const int* __restrict__ row,
                                                     const int* __restrict__ col,
                                                     const unsigned* __restrict__ hashK,
                                                     const int* __restrict__ hashV,
                                                     int* __restrict__ ridx,
                                                     int* rowcnt, int* colcnt, int N, int E) {
    int e = blockIdx.x * 256 + threadIdx.x;
    if (e >= E) return;
    int r = row[e], c = col[e];
    unsigned rkey = (unsigned)c * (unsigned)N + (unsigned)r;
    unsigned h = (rkey * 2654435761u) >> 13; h &= HSM;
    int res = -1;
    while (true) {
        unsigned kk = hashK[h];
        if (kk == rkey) { res = hashV[h]; break; }
        if (kk == 0xFFFFFFFFu) break;
        h = (h + 1) & HSM;
    }
    ridx[e] = res;
    atomicAdd(&rowcnt[r], 1);
    atomicAdd(&colcnt[c], 1);
}

__global__ __launch_bounds__(256) void k_layer_init(unsigned* aggenc, float* outf, float* incf, int NC) {
    int i = blockIdx.x * 256 + threadIdx.x;
    if (i >= NC) return;
    aggenc[i] = ENC_NEGINF;
    outf[i] = 0.f;
    incf[i] = 0.f;
}

// ---------------------------------------------------------------- generic fp32 GEMM
// C[M x Nd] = act(A[M x K] @ B[K x Nd] + bias). 64x64 tile, BK=16, 256 thr, 4x4/thr.
// ACT: 0 none, 1 relu, 2 sigmoid. Nd must be a multiple of 64 (grid.x = Nd/64).

template <int ACT>
__global__ __launch_bounds__(256) void k_gemm(const float* __restrict__ A,
                                              const float* __restrict__ B,
                                              const float* __restrict__ bias,
                                              float* __restrict__ C,
                                              int M, int Nd, int K, int lda, int ldb, int ldc) {
    __shared__ float As[16][64];
    __shared__ float Bs[16][64];
    const int tid = threadIdx.x;
    const int bm = blockIdx.y * 64, bn = blockIdx.x * 64;
    const int tx = tid & 15, ty = tid >> 4;
    const int mload = tid >> 2, k4 = (tid & 3) << 2;
    const int kload = tid >> 4, n4 = (tid & 15) << 2;
    float acc[4][4] = {};
    const int gmload = bm + mload;
    const bool avalid = (gmload < M);
    const float* aptr = A + (size_t)(avalid ? gmload : (M - 1)) * lda + k4;
    const float* bptr = B + (size_t)kload * ldb + bn + n4;
    for (int kb = 0; kb < K; kb += 16) {
        float4 av = avalid ? *(const float4*)(aptr + kb) : make_float4(0.f, 0.f, 0.f, 0.f);
        As[k4 + 0][mload] = av.x; As[k4 + 1][mload] = av.y;
        As[k4 + 2][mload] = av.z; As[k4 + 3][mload] = av.w;
        *(float4*)&Bs[kload][n4] = *(const float4*)(bptr + (size_t)kb * ldb);
        __syncthreads();
#pragma unroll
        for (int k = 0; k < 16; ++k) {
            float4 a = *(const float4*)&As[k][ty << 2];
            float4 b = *(const float4*)&Bs[k][tx << 2];
            acc[0][0] += a.x * b.x; acc[0][1] += a.x * b.y; acc[0][2] += a.x * b.z; acc[0][3] += a.x * b.w;
            acc[1][0] += a.y * b.x; acc[1][1] += a.y * b.y; acc[1][2] += a.y * b.z; acc[1][3] += a.y * b.w;
            acc[2][0] += a.z * b.x; acc[2][1] += a.z * b.y; acc[2][2] += a.z * b.z; acc[2][3] += a.z * b.w;
            acc[3][0] += a.w * b.x; acc[3][1] += a.w * b.y; acc[3][2] += a.w * b.z; acc[3][3] += a.w * b.w;
        }
        __syncthreads();
    }
#pragma unroll
    for (int i = 0; i < 4; ++i) {
        int gm = bm + (ty << 2) + i;
        if (gm >= M) continue;
        float* crow = C + (size_t)gm * ldc;
#pragma unroll
        for (int j = 0; j < 4; ++j) {
            int gn = bn + (tx << 2) + j;
            float v = acc[i][j];
            if (bias) v += bias[gn];
            if (ACT == 1) v = fmaxf(v, 0.f);
            if (ACT == 2) v = 1.f / (1.f + __expf(-v));
            crow[gn] = v;
        }
    }
}

// ---------------------------------------------------------------- edge GEMM 1
// h1[m, 0:384] = relu( [ef[e] | ef[ridx[e]]] @ W(256x384) + eB1 + xa[row[e]] + xb[col[e]] )
// W = eW1 + 128*384 (rows 128..383 of eW1, contiguous). grid = (6, ceil(Mrows/64)).

__global__ __launch_bounds__(256) void k_gemm_edge_h1(const float* __restrict__ ef,
                                                      const int* __restrict__ ridx,
                                                      const float* __restrict__ W,
                                                      const float* __restrict__ eB1,
                                                      const float* __restrict__ xa,
                                                      const float* __restrict__ xb,
                                                      const int* __restrict__ row,
                                                      const int* __restrict__ col,
                                                      float* __restrict__ h1,
                                                      int edgeBase, int Mrows) {
    __shared__ float As[16][64];
    __shared__ float Bs[16][64];
    const int tid = threadIdx.x;
    const int bm = blockIdx.y * 64, bn = blockIdx.x * 64;
    const int tx = tid & 15, ty = tid >> 4;
    const int mload = tid >> 2, k4 = (tid & 3) << 2;
    const int kload = tid >> 4, n4 = (tid & 15) << 2;
    float acc[4][4] = {};
    int ml = min(bm + mload, Mrows - 1);
    int eload = edgeBase + ml;
    const float* arow0 = ef + (size_t)eload * 128;
    int rv = ridx[eload];
    const float* arow1 = (rv >= 0) ? (ef + (size_t)rv * 128) : nullptr;
    const float* bptr = W + (size_t)kload * 384 + bn + n4;
    for (int kb = 0; kb < 256; kb += 16) {
        float4 av;
        if (kb < 128) {
            av = *(const float4*)(arow0 + kb + k4);
        } else {
            av = arow1 ? *(const float4*)(arow1 + (kb - 128) + k4) : make_float4(0.f, 0.f, 0.f, 0.f);
        }
        As[k4 + 0][mload] = av.x; As[k4 + 1][mload] = av.y;
        As[k4 + 2][mload] = av.z; As[k4 + 3][mload] = av.w;
        *(float4*)&Bs[kload][n4] = *(const float4*)(bptr + (size_t)kb * 384);
        __syncthreads();
#pragma unroll
        for (int k = 0; k < 16; ++k) {
            float4 a = *(const float4*)&As[k][ty << 2];
            float4 b = *(const float4*)&Bs[k][tx << 2];
            acc[0][0] += a.x * b.x; acc[0][1] += a.x * b.y; acc[0][2] += a.x * b.z; acc[0][3] += a.x * b.w;
            acc[1][0] += a.y * b.x; acc[1][1] += a.y * b.y; acc[1][2] += a.y * b.z; acc[1][3] += a.y * b.w;
            acc[2][0] += a.z * b.x; acc[2][1] += a.z * b.y; acc[2][2] += a.z * b.z; acc[2][3] += a.z * b.w;
            acc[3][0] += a.w * b.x; acc[3][1] += a.w * b.y; acc[3][2] += a.w * b.z; acc[3][3] += a.w * b.w;
        }
        __syncthreads();
    }
#pragma unroll
    for (int i = 0; i < 4; ++i) {
        int m = bm + (ty << 2) + i;
        if (m >= Mrows) continue;
        int e = edgeBase + m;
        int rb = row[e] * 384, cb = col[e] * 384;
        float* crow = h1 + (size_t)m * 384;
#pragma unroll
        for (int j = 0; j < 4; ++j) {
            int gn = bn + (tx << 2) + j;
            float v = acc[i][j] + eB1[gn] + xa[rb + gn] + xb[cb + gn];
            crow[gn] = fmaxf(v, 0.f);
        }
    }
}

// ---------------------------------------------------------------- edge GEMM 2
// ue = h1 @ eW2(384x128) + eB2; atomicAdd into outf[row]/incf[col]; store relu->efbuf (mid
// layers) or raw->d_out ef region (last layer). grid = (2, ceil(Mrows/64)).

__global__ __launch_bounds__(256) void k_gemm_edge_u(const float* __restrict__ h1,
                                                     const float* __restrict__ eW2,
                                                     const float* __restrict__ eB2,
                                                     const int* __restrict__ row,
                                                     const int* __restrict__ col,
                                                     float* __restrict__ outf,
                                                     float* __restrict__ incf,
                                                     float* __restrict__ dstRelu,
                                                     float* __restrict__ dstRaw,
                                                     int edgeBase, int Mrows) {
    __shared__ float As[16][64];
    __shared__ float Bs[16][64];
    const int tid = threadIdx.x;
    const int bm = blockIdx.y * 64, bn = blockIdx.x * 64;
    const int tx = tid & 15, ty = tid >> 4;
    const int mload = tid >> 2, k4 = (tid & 3) << 2;
    const int kload = tid >> 4, n4 = (tid & 15) << 2;
    float acc[4][4] = {};
    int ml = min(bm + mload, Mrows - 1);
    const float* aptr = h1 + (size_t)ml * 384 + k4;
    const float* bptr = eW2 + (size_t)kload * 128 + bn + n4;
    for (int kb = 0; kb < 384; kb += 16) {
        float4 av = *(const float4*)(aptr + kb);
        As[k4 + 0][mload] = av.x; As[k4 + 1][mload] = av.y;
        As[k4 + 2][mload] = av.z; As[k4 + 3][mload] = av.w;
        *(float4*)&Bs[kload][n4] = *(const float4*)(bptr + (size_t)kb * 128);
        __syncthreads();
#pragma unroll
        for (int k = 0; k < 16; ++k) {
            float4 a = *(const float4*)&As[k][ty << 2];
            float4 b = *(const float4*)&Bs[k][tx << 2];
            acc[0][0] += a.x * b.x; acc[0][1] += a.x * b.y; acc[0][2] += a.x * b.z; acc[0][3] += a.x * b.w;
            acc[1][0] += a.y * b.x; acc[1][1] += a.y * b.y; acc[1][2] += a.y * b.z; acc[1][3] += a.y * b.w;
            acc[2][0] += a.z * b.x; acc[2][1] += a.z * b.y; acc[2][2] += a.z * b.z; acc[2][3] += a.z * b.w;
            acc[3][0] += a.w * b.x; acc[3][1] += a.w * b.y; acc[3][2] += a.w * b.z; acc[3][3] += a.w * b.w;
        }
        __syncthreads();
    }
#pragma unroll
    for (int i = 0; i < 4; ++i) {
        int m = bm + (ty << 2) + i;
        if (m >= Mrows) continue;
        int e = edgeBase + m;
        int rb = row[e] * 128, cb = col[e] * 128;
#pragma unroll
        for (int j = 0; j < 4; ++j) {
            int gn = bn + (tx << 2) + j;
            float v = acc[i][j] + eB2[gn];
            atomicAdd(&outf[rb + gn], v);
            atomicAdd(&incf[cb + gn], v);
            if (dstRelu) dstRelu[(size_t)e * 128 + gn] = fmaxf(v, 0.f);
            else dstRaw[(size_t)e * 128 + gn] = v;
        }
    }
}

// ---------------------------------------------------------------- attention kernel
// One wave per edge (grid-stride). Computes dm-MLP, h1/att einsums, softmax, prob out,
// wv = prob * v, and atomicMax-encoded scatter into aggenc[row].

__global__ __launch_bounds__(256) void k_attn(const float* __restrict__ xq,
                                              const float* __restrict__ kbuf,
                                              const float* __restrict__ xv,
                                              const float* __restrict__ desc,
                                              const int* __restrict__ row,
                                              const int* __restrict__ col,
                                              const float* __restrict__ attW1,
                                              const float* __restrict__ attB1,
                                              const float* __restrict__ attW2,
                                              const float* __restrict__ attB2,
                                              const float* __restrict__ dW1,
                                              const float* __restrict__ dB1,
                                              const float* __restrict__ dW2,
                                              const float* __restrict__ dB2,
                                              float* __restrict__ prob_out,
                                              unsigned* __restrict__ aggenc, int E) {
    __shared__ float w1[32 * 33];   // padded: w1[o*33+c]
    __shared__ float w2[16 * 33];
    __shared__ float sdw1[128];
    for (int i = threadIdx.x; i < 1024; i += 256) w1[(i >> 5) * 33 + (i & 31)] = attW1[i];
    for (int i = threadIdx.x; i < 512; i += 256) w2[(i >> 5) * 33 + (i & 31)] = attW2[i];
    for (int i = threadIdx.x; i < 128; i += 256) sdw1[i] = dW1[i];
    __syncthreads();

    const int lane = threadIdx.x & 63;
    const int hd = lane & 7;       // head index
    const int og = lane >> 3;      // 0..7: o-group for h1 (4 o's) and att (2 o2's)
    const int c32 = lane & 31;
    const int nw = (gridDim.x * 256) >> 6;
    int wid = (blockIdx.x * 256 + threadIdx.x) >> 6;

    const float b1_0 = attB1[og * 4 + 0], b1_1 = attB1[og * 4 + 1];
    const float b1_2 = attB1[og * 4 + 2], b1_3 = attB1[og * 4 + 3];
    const float b2_0 = attB2[og * 2 + 0], b2_1 = attB2[og * 2 + 1];
    const float db2v = dB2[0];
    const float dw2v = dW2[c32];
    const float db1v = dB1[c32];

    for (int e = wid; e < E; e += nw) {
        int r = row[e], cl = col[e];
        // --- distance gate dm
        float dx = desc[r * 8 + 0] - desc[cl * 8 + 0];
        float dy = desc[r * 8 + 1] - desc[cl * 8 + 1];
        float dz = desc[r * 8 + 2] - desc[cl * 8 + 2];
        float dist = sqrtf(dx * dx + dy * dy + dz * dz);
        float t = db1v + dx * sdw1[c32] + dy * sdw1[32 + c32] + dz * sdw1[64 + c32] + dist * sdw1[96 + c32];
        t = fmaxf(t, 0.f) * dw2v;
        t += __shfl_xor(t, 1, 64); t += __shfl_xor(t, 2, 64); t += __shfl_xor(t, 4, 64);
        t += __shfl_xor(t, 8, 64); t += __shfl_xor(t, 16, 64);
        float dm = 1.f / (1.f + __expf(-(t + db2v)));

        const float* qrow = xq + (size_t)r * 128;
        const float* krow = kbuf + (size_t)e * 128;
        // --- h1[o][hd] for o = og*4 .. og*4+3
        float h0 = b1_0, h1v = b1_1, h2 = b1_2, h3 = b1_3;
#pragma unroll
        for (int ci = 0; ci < 16; ++ci) {
            float hv = qrow[ci * 8 + hd];
            h0 += hv * w1[(og * 4 + 0) * 33 + ci];
            h1v += hv * w1[(og * 4 + 1) * 33 + ci];
            h2 += hv * w1[(og * 4 + 2) * 33 + ci];
            h3 += hv * w1[(og * 4 + 3) * 33 + ci];
        }
#pragma unroll
        for (int ci = 0; ci < 16; ++ci) {
            float hv = krow[ci * 8 + hd];
            h0 += hv * w1[(og * 4 + 0) * 33 + 16 + ci];
            h1v += hv * w1[(og * 4 + 1) * 33 + 16 + ci];
            h2 += hv * w1[(og * 4 + 2) * 33 + 16 + ci];
            h3 += hv * w1[(og * 4 + 3) * 33 + 16 + ci];
        }
        float hreg[4];
        hreg[0] = fmaxf(h0, 0.f); hreg[1] = fmaxf(h1v, 0.f);
        hreg[2] = fmaxf(h2, 0.f); hreg[3] = fmaxf(h3, 0.f);
        // --- att[o2][hd] for o2 = og*2, og*2+1
        float a0 = b2_0, a1 = b2_1;
#pragma unroll
        for (int c = 0; c < 32; ++c) {
            int src = (c >> 2) * 8 + hd;
            float hv = __shfl(hreg[c & 3], src, 64);
            a0 += hv * w2[(og * 2 + 0) * 33 + c];
            a1 += hv * w2[(og * 2 + 1) * 33 + c];
        }
        float sc = dm * 0.25f;   // * dm, / temp (temp = sqrt(16) = 4)
        a0 *= sc; a1 *= sc;
        // --- softmax over the 16 o2's (lanes with same hd)
        float mx = fmaxf(a0, a1);
        mx = fmaxf(mx, __shfl_xor(mx, 8, 64));
        mx = fmaxf(mx, __shfl_xor(mx, 16, 64));
        mx = fmaxf(mx, __shfl_xor(mx, 32, 64));
        float e0 = __expf(a0 - mx), e1 = __expf(a1 - mx);
        float s = e0 + e1;
        s += __shfl_xor(s, 8, 64); s += __shfl_xor(s, 16, 64); s += __shfl_xor(s, 32, 64);
        float inv = 1.f / s;
        float p0 = e0 * inv, p1 = e1 * inv;
        size_t base = (size_t)e * 128 + og * 16 + hd;
        prob_out[base] = p0;
        prob_out[base + 8] = p1;
        // --- wv + segment-max scatter
        const float* vrow = xv + (size_t)cl * 128;
        float v0 = vrow[og * 16 + hd] * p0;
        float v1 = vrow[og * 16 + hd + 8] * p1;
        unsigned* ab = aggenc + (size_t)r * 128 + og * 16 + hd;
        atomicMax(ab, encf(v0));
        atomicMax(ab + 8, encf(v1));
    }
}

// ---------------------------------------------------------------- small elementwise kernels

__global__ __launch_bounds__(256) void k_ncat(const float* __restrict__ x,
                                              const unsigned* __restrict__ aggenc,
                                              float* __restrict__ ncat, int N) {
    int i = blockIdx.x * 256 + threadIdx.x;
    if (i >= N * 256) return;
    int n = i >> 8, c = i & 255;
    float v;
    if (c < 128) v = x[n * 128 + c];
    else {
        unsigned u = aggenc[n * 128 + c - 128];
        v = (u == ENC_NEGINF) ? 0.f : decf(u);
    }
    ncat[i] = v;
}

__global__ __launch_bounds__(256) void k_cat2(const float* __restrict__ outf,
                                              const float* __restrict__ incf,
                                              const int* __restrict__ rowcnt,
                                              const int* __restrict__ colcnt,
                                              float* __restrict__ cat2, int N) {
    int i = blockIdx.x * 256 + threadIdx.x;
    if (i >= N * 256) return;
    int n = i >> 8, c = i & 255;
    float v;
    if (c < 128) v = outf[n * 128 + c] / fmaxf((float)rowcnt[n], 1.f);
    else v = incf[n * 128 + c - 128] / fmaxf((float)colcnt[n], 1.f);
    cat2[i] = v;
}

__global__ __launch_bounds__(256) void k_final(const float* __restrict__ un,
                                               const float* __restrict__ eatt,
                                               float* __restrict__ dst, int NC) {
    int i = blockIdx.x * 256 + threadIdx.x;
    if (i >= NC) return;
    dst[i] = fmaxf(un[i], 0.f) * eatt[i];
}

// ---------------------------------------------------------------- host orchestration

extern "C" void kernel_launch(void* const* d_in, const int* in_sizes, int n_in,
                              void* d_out, int out_size, void* d_ws, size_t ws_size,
                              hipStream_t stream) {
    const float* node_feature = (const float*)d_in[0];
    const float* edge_feature = (const float*)d_in[1];
    const int* edges = (const int*)d_in[2];
    const float* desc = (const float*)d_in[3];
    const float* qW = (const float*)d_in[4];
    const float* qB = (const float*)d_in[5];
    const float* kW = (const float*)d_in[6];
    const float* kB = (const float*)d_in[7];
    const float* vW = (const float*)d_in[8];
    const float* vB = (const float*)d_in[9];
    const float* dW1 = (const float*)d_in[10];
    const float* dB1 = (const float*)d_in[11];
    const float* dW2 = (const float*)d_in[12];
    const float* dB2 = (const float*)d_in[13];
    const float* eW1 = (const float*)d_in[14];
    const float* eB1 = (const float*)d_in[15];
    const float* eW2 = (const float*)d_in[16];
    const float* eB2 = (const float*)d_in[17];
    const float* attW1 = (const float*)d_in[18];
    const float* attB1 = (const float*)d_in[19];
    const float* attW2 = (const float*)d_in[20];
    const float* attB2 = (const float*)d_in[21];
    const float* nW1 = (const float*)d_in[22];
    const float* nB1 = (const float*)d_in[23];
    const float* nW2 = (const float*)d_in[24];
    const float* nB2 = (const float*)d_in[25];
    const float* aW = (const float*)d_in[26];
    const float* aB = (const float*)d_in[27];

    const int N = in_sizes[0] / 128;
    const int E = in_sizes[2] / 2;
    const int L = 2;
    const int* row = edges;
    const int* col = edges + E;

    // workspace carve
    char* wsp = (char*)d_ws;
    auto alloc = [&](size_t bytes) {
        char* p = wsp;
        wsp += (bytes + 255) & ~(size_t)255;
        return p;
    };
    unsigned* hashK = (unsigned*)alloc((size_t)HS * 4);
    int* hashV = (int*)alloc((size_t)HS * 4);
    int* ridx = (int*)alloc((size_t)E * 4);
    int* rowcnt = (int*)alloc((size_t)N * 4);
    int* colcnt = (int*)alloc((size_t)N * 4);
    float* xq = (float*)alloc((size_t)N * 128 * 4);
    float* xv = (float*)alloc((size_t)N * 128 * 4);
    float* xa = (float*)alloc((size_t)N * 384 * 4);
    float* xb = (float*)alloc((size_t)N * 384 * 4);
    float* kbuf = (float*)alloc((size_t)E * 128 * 4);
    float* efbuf = (float*)alloc((size_t)E * 128 * 4);
    const int CH = 32000;
    float* h1c = (float*)alloc((size_t)CH * 384 * 4);
    unsigned* aggenc = (unsigned*)alloc((size_t)N * 128 * 4);
    float* ncat = (float*)alloc((size_t)N * 256 * 4);
    float* nh1 = (float*)alloc((size_t)N * 256 * 4);
    float* un = (float*)alloc((size_t)N * 128 * 4);
    float* outf = (float*)alloc((size_t)N * 128 * 4);
    float* incf = (float*)alloc((size_t)N * 128 * 4);
    float* cat2 = (float*)alloc((size_t)N * 256 * 4);
    float* eattb = (float*)alloc((size_t)N * 128 * 4);
    float* xbuf = (float*)alloc((size_t)N * 128 * 4);

    float* out_x = (float*)d_out;
    float* out_ef = out_x + (size_t)N * 128;
    float* out_prob = out_ef + (size_t)E * 128;

    // --- static (per-call) setup: reverse-edge map + degrees
    k_init_static<<<(HS + 255) / 256, 256, 0, stream>>>(hashK, hashV, rowcnt, colcnt, N);
    k_hash_insert<<<(E + 255) / 256, 256, 0, stream>>>(row, col, hashK, hashV, N, E);
    k_hash_lookup<<<(E + 255) / 256, 256, 0, stream>>>(row, col, hashK, hashV, ridx, rowcnt, colcnt, N, E);

    for (int l = 0; l < L; ++l) {
        const float* x_cur = (l == 0) ? node_feature : xbuf;
        const float* ef_cur = (l == 0) ? edge_feature : efbuf;
        const bool last = (l == L - 1);

        const float* qW_l = qW + (size_t)l * 128 * 128;
        const float* qB_l = qB + (size_t)l * 128;
        const float* kW_l = kW + (size_t)l * 128 * 128;
        const float* kB_l = kB + (size_t)l * 128;
        const float* vW_l = vW + (size_t)l * 128 * 128;
        const float* vB_l = vB + (size_t)l * 128;
        const float* dW1_l = dW1 + (size_t)l * 128;
        const float* dB1_l = dB1 + (size_t)l * 32;
        const float* dW2_l = dW2 + (size_t)l * 32;
        const float* dB2_l = dB2 + (size_t)l * 1;
        const float* eW1_l = eW1 + (size_t)l * 512 * 384;
        const float* eB1_l = eB1 + (size_t)l * 384;
        const float* eW2_l = eW2 + (size_t)l * 384 * 128;
        const float* eB2_l = eB2 + (size_t)l * 128;
        const float* attW1_l = attW1 + (size_t)l * 32 * 32;
        const float* attB1_l = attB1 + (size_t)l * 32;
        const float* attW2_l = attW2 + (size_t)l * 16 * 32;
        const float* attB2_l = attB2 + (size_t)l * 16;
        const float* nW1_l = nW1 + (size_t)l * 256 * 256;
        const float* nB1_l = nB1 + (size_t)l * 256;
        const float* nW2_l = nW2 + (size_t)l * 256 * 128;
        const float* nB2_l = nB2 + (size_t)l * 128;
        const float* aW_l = aW + (size_t)l * 256 * 128;
        const float* aB_l = aB + (size_t)l * 128;

        k_layer_init<<<(N * 128 + 255) / 256, 256, 0, stream>>>(aggenc, outf, incf, N * 128);

        int gy_n = (N + 63) / 64;
        // per-node precomputes
        k_gemm<0><<<dim3(2, gy_n), 256, 0, stream>>>(x_cur, qW_l, qB_l, xq, N, 128, 128, 128, 128, 128);
        k_gemm<0><<<dim3(2, gy_n), 256, 0, stream>>>(x_cur, vW_l, vB_l, xv, N, 128, 128, 128, 128, 128);
        k_gemm<0><<<dim3(6, gy_n), 256, 0, stream>>>(x_cur, eW1_l, nullptr, xa, N, 384, 128, 128, 384, 384);
        k_gemm<0><<<dim3(6, gy_n), 256, 0, stream>>>(x_cur, eW1_l + (size_t)384 * 384, nullptr, xb, N, 384, 128, 128, 384, 384);
        // per-edge k projection
        k_gemm<0><<<dim3(2, (E + 63) / 64), 256, 0, stream>>>(ef_cur, kW_l, kB_l, kbuf, E, 128, 128, 128, 128, 128);
        // attention + prob + segment-max
        k_attn<<<2048, 256, 0, stream>>>(xq, kbuf, xv, desc, row, col, attW1_l, attB1_l, attW2_l, attB2_l,
                                         dW1_l, dB1_l, dW2_l, dB2_l,
                                         out_prob + (size_t)l * E * 128, aggenc, E);
        // edge MLP in chunks
        for (int cb = 0; cb < E; cb += CH) {
            int mrows = (E - cb < CH) ? (E - cb) : CH;
            int gy = (mrows + 63) / 64;
            k_gemm_edge_h1<<<dim3(6, gy), 256, 0, stream>>>(ef_cur, ridx, eW1_l + (size_t)128 * 384, eB1_l,
                                                            xa, xb, row, col, h1c, cb, mrows);
            k_gemm_edge_u<<<dim3(2, gy), 256, 0, stream>>>(h1c, eW2_l, eB2_l, row, col, outf, incf,
                                                           last ? nullptr : efbuf,
                                                           last ? out_ef : nullptr, cb, mrows);
        }
        // node update
        k_ncat<<<(N * 256 + 255) / 256, 256, 0, stream>>>(x_cur, aggenc, ncat, N);
        k_gemm<1><<<dim3(4, gy_n), 256, 0, stream>>>(ncat, nW1_l, nB1_l, nh1, N, 256, 256, 256, 256, 256);
        k_gemm<0><<<dim3(2, gy_n), 256, 0, stream>>>(nh1, nW2_l, nB2_l, un, N, 128, 256, 256, 128, 128);
        k_cat2<<<(N * 256 + 255) / 256, 256, 0, stream>>>(outf, incf, rowcnt, colcnt, cat2, N);
        k_gemm<2><<<dim3(2, gy_n), 256, 0, stream>>>(cat2, aW_l, aB_l, eattb, N, 128, 256, 256, 128, 128);
        k_final<<<(N * 128 + 255) / 256, 256, 0, stream>>>(un, eattb, last ? out_x : xbuf, N * 128);
    }
}

// Round 2
// 3588.245 us; speedup vs baseline: 1.2524x; 1.2524x over previous
//
#include <hip/hip_runtime.h>
#include <math.h>

#define HS 524288
#define HSM (HS - 1)
#define ENC_NEGINF 0x007FFFFFu

__device__ __forceinline__ unsigned encf(float f) {
    unsigned b = __float_as_uint(f);
    return (b & 0x80000000u) ? ~b : (b | 0x80000000u);
}
__device__ __forceinline__ float decf(unsigned u) {
    return __uint_as_float((u & 0x80000000u) ? (u & 0x7FFFFFFFu) : ~u);
}

// ---------------------------------------------------------------- setup kernels

__global__ __launch_bounds__(256) void k_init_static(unsigned* hashK, int* hashV,
                                                     int* rowcnt, int* colcnt, int N) {
    int i = blockIdx.x * 256 + threadIdx.x;
    if (i < HS) { hashK[i] = 0xFFFFFFFFu; hashV[i] = 0x7FFFFFFF; }
    if (i < N) { rowcnt[i] = 0; colcnt[i] = 0; }
}

__global__ __launch_bounds__(256) void k_hash_insert(const int* __restrict__ row,
                                                     const int* __restrict__ col,
                                                     unsigned* hashK, int* hashV, int N, int E) {
    int e = blockIdx.x * 256 + threadIdx.x;
    if (e >= E) return;
    unsigned key = (unsigned)row[e] * (unsigned)N + (unsigned)col[e];
    unsigned h = (key * 2654435761u) >> 13; h &= HSM;
    while (true) {
        unsigned prev = atomicCAS(&hashK[h], 0xFFFFFFFFu, key);
        if (prev == 0xFFFFFFFFu || prev == key) { atomicMin(&hashV[h], e); break; }
        h = (h + 1) & HSM;
    }
}

__global__ __launch_bounds__(256) void k_hash_lookup(const int* __restrict__ row,
                                                     const int* __restrict__ col,
                                                     const unsigned* __restrict__ hashK,
                                                     const int* __restrict__ hashV,
                                                     int* __restrict__ ridx,
                                                     int* rowcnt, int* colcnt, int N, int E) {
    int e = blockIdx.x * 256 + threadIdx.x;
    if (e >= E) return;
    int r = row[e], c = col[e];
    unsigned rkey = (unsigned)c * (unsigned)N + (unsigned)r;
    unsigned h = (rkey * 2654435761u) >> 13; h &= HSM;
    int res = -1;
    while (true) {
        unsigned kk = hashK[h];
        if (kk == rkey) { res = hashV[h]; break; }
        if (kk == 0xFFFFFFFFu) break;
        h = (h + 1) & HSM;
    }
    ridx[e] = res;
    atomicAdd(&rowcnt[r], 1);
    atomicAdd(&colcnt[c], 1);
}

__global__ __launch_bounds__(256) void k_layer_init(unsigned* aggenc, float* outf, float* incf, int NC) {
    int i = blockIdx.x * 256 + threadIdx.x;
    if (i >= NC) return;
    aggenc[i] = ENC_NEGINF;
    outf[i] = 0.f;
    incf[i] = 0.f;
}

// ---------------------------------------------------------------- generic fp32 GEMM
// C[M x Nd] = act(A[M x K] @ B[K x Nd] + bias). 64x64 tile, BK=16, 256 thr, 4x4/thr.
// ACT: 0 none, 1 relu, 2 sigmoid. Nd must be a multiple of 64 (grid.x = Nd/64).

template <int ACT>
__global__ __launch_bounds__(256) void k_gemm(const float* __restrict__ A,
                                              const float* __restrict__ B,
                                              const float* __restrict__ bias,
                                              float* __restrict__ C,
                                              int M, int Nd, int K, int lda, int ldb, int ldc) {
    __shared__ float As[16][64];
    __shared__ float Bs[16][64];
    const int tid = threadIdx.x;
    const int bm = blockIdx.y * 64, bn = blockIdx.x * 64;
    const int tx = tid & 15, ty = tid >> 4;
    const int mload = tid >> 2, k4 = (tid & 3) << 2;
    const int kload = tid >> 4, n4 = (tid & 15) << 2;
    float acc[4][4] = {};
    const int gmload = bm + mload;
    const bool avalid = (gmload < M);
    const float* aptr = A + (size_t)(avalid ? gmload : (M - 1)) * lda + k4;
    const float* bptr = B + (size_t)kload * ldb + bn + n4;
    for (int kb = 0; kb < K; kb += 16) {
        float4 av = avalid ? *(const float4*)(aptr + kb) : make_float4(0.f, 0.f, 0.f, 0.f);
        As[k4 + 0][mload] = av.x; As[k4 + 1][mload] = av.y;
        As[k4 + 2][mload] = av.z; As[k4 + 3][mload] = av.w;
        *(float4*)&Bs[kload][n4] = *(const float4*)(bptr + (size_t)kb * ldb);
        __syncthreads();
#pragma unroll
        for (int k = 0; k < 16; ++k) {
            float4 a = *(const float4*)&As[k][ty << 2];
            float4 b = *(const float4*)&Bs[k][tx << 2];
            acc[0][0] += a.x * b.x; acc[0][1] += a.x * b.y; acc[0][2] += a.x * b.z; acc[0][3] += a.x * b.w;
            acc[1][0] += a.y * b.x; acc[1][1] += a.y * b.y; acc[1][2] += a.y * b.z; acc[1][3] += a.y * b.w;
            acc[2][0] += a.z * b.x; acc[2][1] += a.z * b.y; acc[2][2] += a.z * b.z; acc[2][3] += a.z * b.w;
            acc[3][0] += a.w * b.x; acc[3][1] += a.w * b.y; acc[3][2] += a.w * b.z; acc[3][3] += a.w * b.w;
        }
        __syncthreads();
    }
#pragma unroll
    for (int i = 0; i < 4; ++i) {
        int gm = bm + (ty << 2) + i;
        if (gm >= M) continue;
        float* crow = C + (size_t)gm * ldc;
#pragma unroll
        for (int j = 0; j < 4; ++j) {
            int gn = bn + (tx << 2) + j;
            float v = acc[i][j];
            if (bias) v += bias[gn];
            if (ACT == 1) v = fmaxf(v, 0.f);
            if (ACT == 2) v = 1.f / (1.f + __expf(-v));
            crow[gn] = v;
        }
    }
}

// ---------------------------------------------------------------- edge GEMM 1
// h1[m, 0:384] = relu( [ef[e] | ef[ridx[e]]] @ W(256x384) + eB1 + xa[row[e]] + xb[col[e]] )
// W = eW1 + 128*384 (rows 128..383 of eW1, contiguous). grid = (6, ceil(Mrows/64)).

__global__ __launch_bounds__(256) void k_gemm_edge_h1(const float* __restrict__ ef,
                                                      const int* __restrict__ ridx,
                                                      const float* __restrict__ W,
                                                      const float* __restrict__ eB1,
                                                      const float* __restrict__ xa,
                                                      const float* __restrict__ xb,
                                                      const int* __restrict__ row,
                                                      const int* __restrict__ col,
                                                      float* __restrict__ h1,
                                                      int edgeBase, int Mrows) {
    __shared__ float As[16][64];
    __shared__ float Bs[16][64];
    const int tid = threadIdx.x;
    const int bm = blockIdx.y * 64, bn = blockIdx.x * 64;
    const int tx = tid & 15, ty = tid >> 4;
    const int mload = tid >> 2, k4 = (tid & 3) << 2;
    const int kload = tid >> 4, n4 = (tid & 15) << 2;
    float acc[4][4] = {};
    int ml = min(bm + mload, Mrows - 1);
    int eload = edgeBase + ml;
    const float* arow0 = ef + (size_t)eload * 128;
    int rv = ridx[eload];
    const float* arow1 = (rv >= 0) ? (ef + (size_t)rv * 128) : nullptr;
    const float* bptr = W + (size_t)kload * 384 + bn + n4;
    for (int kb = 0; kb < 256; kb += 16) {
        float4 av;
        if (kb < 128) {
            av = *(const float4*)(arow0 + kb + k4);
        } else {
            av = arow1 ? *(const float4*)(arow1 + (kb - 128) + k4) : make_float4(0.f, 0.f, 0.f, 0.f);
        }
        As[k4 + 0][mload] = av.x; As[k4 + 1][mload] = av.y;
        As[k4 + 2][mload] = av.z; As[k4 + 3][mload] = av.w;
        *(float4*)&Bs[kload][n4] = *(const float4*)(bptr + (size_t)kb * 384);
        __syncthreads();
#pragma unroll
        for (int k = 0; k < 16; ++k) {
            float4 a = *(const float4*)&As[k][ty << 2];
            float4 b = *(const float4*)&Bs[k][tx << 2];
            acc[0][0] += a.x * b.x; acc[0][1] += a.x * b.y; acc[0][2] += a.x * b.z; acc[0][3] += a.x * b.w;
            acc[1][0] += a.y * b.x; acc[1][1] += a.y * b.y; acc[1][2] += a.y * b.z; acc[1][3] += a.y * b.w;
            acc[2][0] += a.z * b.x; acc[2][1] += a.z * b.y; acc[2][2] += a.z * b.z; acc[2][3] += a.z * b.w;
            acc[3][0] += a.w * b.x; acc[3][1] += a.w * b.y; acc[3][2] += a.w * b.z; acc[3][3] += a.w * b.w;
        }
        __syncthreads();
    }
#pragma unroll
    for (int i = 0; i < 4; ++i) {
        int m = bm + (ty << 2) + i;
        if (m >= Mrows) continue;
        int e = edgeBase + m;
        int rb = row[e] * 384, cb = col[e] * 384;
        float* crow = h1 + (size_t)m * 384;
#pragma unroll
        for (int j = 0; j < 4; ++j) {
            int gn = bn + (tx << 2) + j;
            float v = acc[i][j] + eB1[gn] + xa[rb + gn] + xb[cb + gn];
            crow[gn] = fmaxf(v, 0.f);
        }
    }
}

// ---------------------------------------------------------------- edge GEMM 2
// ue = h1 @ eW2(384x128) + eB2; atomicAdd into outf[row]/incf[col]; store relu->efbuf (mid
// layers) or raw->d_out ef region (last layer). grid = (2, ceil(Mrows/64)).

__global__ __launch_bounds__(256) void k_gemm_edge_u(const float* __restrict__ h1,
                                                     const float* __restrict__ eW2,
                                                     const float* __restrict__ eB2,
                                                     const int* __restrict__ row,
                                                     const int* __restrict__ col,
                                                     float* __restrict__ outf,
                                                     float* __restrict__ incf,
                                                     float* __restrict__ dstRelu,
                                                     float* __restrict__ dstRaw,
                                                     int edgeBase, int Mrows) {
    __shared__ float As[16][64];
    __shared__ float Bs[16][64];
    const int tid = threadIdx.x;
    const int bm = blockIdx.y * 64, bn = blockIdx.x * 64;
    const int tx = tid & 15, ty = tid >> 4;
    const int mload = tid >> 2, k4 = (tid & 3) << 2;
    const int kload = tid >> 4, n4 = (tid & 15) << 2;
    float acc[4][4] = {};
    int ml = min(bm + mload, Mrows - 1);
    const float* aptr = h1 + (size_t)ml * 384 + k4;
    const float* bptr = eW2 + (size_t)kload * 128 + bn + n4;
    for (int kb = 0; kb < 384; kb += 16) {
        float4 av = *(const float4*)(aptr + kb);
        As[k4 + 0][mload] = av.x; As[k4 + 1][mload] = av.y;
        As[k4 + 2][mload] = av.z; As[k4 + 3][mload] = av.w;
        *(float4*)&Bs[kload][n4] = *(const float4*)(bptr + (size_t)kb * 128);
        __syncthreads();
#pragma unroll
        for (int k = 0; k < 16; ++k) {
            float4 a = *(const float4*)&As[k][ty << 2];
            float4 b = *(const float4*)&Bs[k][tx << 2];
            acc[0][0] += a.x * b.x; acc[0][1] += a.x * b.y; acc[0][2] += a.x * b.z; acc[0][3] += a.x * b.w;
            acc[1][0] += a.y * b.x; acc[1][1] += a.y * b.y; acc[1][2] += a.y * b.z; acc[1][3] += a.y * b.w;
            acc[2][0] += a.z * b.x; acc[2][1] += a.z * b.y; acc[2][2] += a.z * b.z; acc[2][3] += a.z * b.w;
            acc[3][0] += a.w * b.x; acc[3][1] += a.w * b.y; acc[3][2] += a.w * b.z; acc[3][3] += a.w * b.w;
        }
        __syncthreads();
    }
#pragma unroll
    for (int i = 0; i < 4; ++i) {
        int m = bm + (ty << 2) + i;
        if (m >= Mrows) continue;
        int e = edgeBase + m;
        int rb = row[e] * 128, cb = col[e] * 128;
#pragma unroll
        for (int j = 0; j < 4; ++j) {
            int gn = bn + (tx << 2) + j;
            float v = acc[i][j] + eB2[gn];
            atomicAdd(&outf[rb + gn], v);
            atomicAdd(&incf[cb + gn], v);
            if (dstRelu) dstRelu[(size_t)e * 128 + gn] = fmaxf(v, 0.f);
            else dstRaw[(size_t)e * 128 + gn] = v;
        }
    }
}

// ---------------------------------------------------------------- attention kernel
// One wave per edge (grid-stride). q/k/v rows staged via LDS with coalesced float2
// global loads; attW1/attW2 transposed+padded in LDS so per-lane weight reads are
// ds_read_b128/b64; prob written coalesced via LDS bounce.

__global__ __launch_bounds__(256) void k_attn(const float* __restrict__ xq,
                                              const float* __restrict__ kbuf,
                                              const float* __restrict__ xv,
                                              const float* __restrict__ desc,
                                              const int* __restrict__ row,
                                              const int* __restrict__ col,
                                              const float* __restrict__ attW1,
                                              const float* __restrict__ attB1,
                                              const float* __restrict__ attW2,
                                              const float* __restrict__ attB2,
                                              const float* __restrict__ dW1,
                                              const float* __restrict__ dB1,
                                              const float* __restrict__ dW2,
                                              const float* __restrict__ dB2,
                                              float* __restrict__ prob_out,
                                              unsigned* __restrict__ aggenc, int E) {
    __shared__ float w1t[32 * 36];  // w1t[c*36+o] = attW1[o*32+c], o in 0..31
    __shared__ float w2t[32 * 18];  // w2t[c*18+o] = attW2[o*32+c], o in 0..15
    __shared__ float sdw1[128];
    __shared__ float sQ[4][128];
    __shared__ float sK[4][128];
    __shared__ float sV[4][128];
    __shared__ float sP[4][128];
    for (int i = threadIdx.x; i < 1024; i += 256) {
        int o = i >> 5, c = i & 31;
        w1t[c * 36 + o] = attW1[i];
    }
    for (int i = threadIdx.x; i < 512; i += 256) {
        int o = i >> 5, c = i & 31;
        w2t[c * 18 + o] = attW2[i];
    }
    for (int i = threadIdx.x; i < 128; i += 256) sdw1[i] = dW1[i];
    __syncthreads();

    const int wv = threadIdx.x >> 6;
    const int lane = threadIdx.x & 63;
    const int hd = lane & 7;       // head index
    const int og = lane >> 3;      // 0..7: o-group for h1 (4 o's) and att (2 o2's)
    const int c32 = lane & 31;
    const int nw = (gridDim.x * 256) >> 6;
    const int wid = (blockIdx.x * 256 + threadIdx.x) >> 6;

    float* myQ = sQ[wv];
    float* myK = sK[wv];
    float* myV = sV[wv];
    float* myP = sP[wv];

    const float b1_0 = attB1[og * 4 + 0], b1_1 = attB1[og * 4 + 1];
    const float b1_2 = attB1[og * 4 + 2], b1_3 = attB1[og * 4 + 3];
    const float b2_0 = attB2[og * 2 + 0], b2_1 = attB2[og * 2 + 1];
    const float db2v = dB2[0];
    const float dw2v = dW2[c32];
    const float db1v = dB1[c32];

    for (int e0 = wid; e0 < E; e0 += nw) {
        const int e = __builtin_amdgcn_readfirstlane(e0);
        const int r = row[e], cl = col[e];
        // --- coalesced staging: q/k/v rows -> LDS (float2 per lane)
        float2 qv = *(const float2*)(xq + (size_t)r * 128 + lane * 2);
        float2 kv = *(const float2*)(kbuf + (size_t)e * 128 + lane * 2);
        float2 vv = *(const float2*)(xv + (size_t)cl * 128 + lane * 2);
        *(float2*)(myQ + lane * 2) = qv;
        *(float2*)(myK + lane * 2) = kv;
        *(float2*)(myV + lane * 2) = vv;
        __builtin_amdgcn_wave_barrier();

        // --- distance gate dm (desc reads are scalar: r, cl wave-uniform)
        float dx = desc[r * 8 + 0] - desc[cl * 8 + 0];
        float dy = desc[r * 8 + 1] - desc[cl * 8 + 1];
        float dz = desc[r * 8 + 2] - desc[cl * 8 + 2];
        float dist = sqrtf(dx * dx + dy * dy + dz * dz);
        float t = db1v + dx * sdw1[c32] + dy * sdw1[32 + c32] + dz * sdw1[64 + c32] + dist * sdw1[96 + c32];
        t = fmaxf(t, 0.f) * dw2v;
        t += __shfl_xor(t, 1, 64); t += __shfl_xor(t, 2, 64); t += __shfl_xor(t, 4, 64);
        t += __shfl_xor(t, 8, 64); t += __shfl_xor(t, 16, 64);
        float dm = 1.f / (1.f + __expf(-(t + db2v)));

        // --- h1[o][hd] for o = og*4 .. og*4+3 (weights via ds_read_b128)
        float h0 = b1_0, h1v = b1_1, h2 = b1_2, h3 = b1_3;
#pragma unroll
        for (int ci = 0; ci < 16; ++ci) {
            float hv = myQ[ci * 8 + hd];
            const float4 w = *(const float4*)&w1t[ci * 36 + og * 4];
            h0 += hv * w.x; h1v += hv * w.y; h2 += hv * w.z; h3 += hv * w.w;
        }
#pragma unroll
        for (int ci = 0; ci < 16; ++ci) {
            float hv = myK[ci * 8 + hd];
            const float4 w = *(const float4*)&w1t[(16 + ci) * 36 + og * 4];
            h0 += hv * w.x; h1v += hv * w.y; h2 += hv * w.z; h3 += hv * w.w;
        }
        float hreg[4];
        hreg[0] = fmaxf(h0, 0.f); hreg[1] = fmaxf(h1v, 0.f);
        hreg[2] = fmaxf(h2, 0.f); hreg[3] = fmaxf(h3, 0.f);

        // --- att[o2][hd] for o2 = og*2, og*2+1
        float a0 = b2_0, a1 = b2_1;
#pragma unroll
        for (int c = 0; c < 32; ++c) {
            int src = (c >> 2) * 8 + hd;
            float hv = __shfl(hreg[c & 3], src, 64);
            const float2 w = *(const float2*)&w2t[c * 18 + og * 2];
            a0 += hv * w.x; a1 += hv * w.y;
        }
        float sc = dm * 0.25f;   // * dm, / temp (temp = sqrt(16) = 4)
        a0 *= sc; a1 *= sc;

        // --- softmax over the 16 o2's (lanes with same hd)
        float mx = fmaxf(a0, a1);
        mx = fmaxf(mx, __shfl_xor(mx, 8, 64));
        mx = fmaxf(mx, __shfl_xor(mx, 16, 64));
        mx = fmaxf(mx, __shfl_xor(mx, 32, 64));
        float e0v = __expf(a0 - mx), e1v = __expf(a1 - mx);
        float s = e0v + e1v;
        s += __shfl_xor(s, 8, 64); s += __shfl_xor(s, 16, 64); s += __shfl_xor(s, 32, 64);
        float inv = 1.f / s;
        float p0 = e0v * inv, p1 = e1v * inv;

        // --- stage prob row in LDS, write coalesced
        myP[og * 16 + hd] = p0;
        myP[og * 16 + hd + 8] = p1;

        // --- wv + segment-max scatter
        float v0 = myV[og * 16 + hd] * p0;
        float v1 = myV[og * 16 + hd + 8] * p1;
        unsigned* ab = aggenc + (size_t)r * 128 + og * 16 + hd;
        atomicMax(ab, encf(v0));
        atomicMax(ab + 8, encf(v1));

        __builtin_amdgcn_wave_barrier();
        *(float2*)(prob_out + (size_t)e * 128 + lane * 2) = *(const float2*)(myP + lane * 2);
    }
}

// ---------------------------------------------------------------- small elementwise kernels

__global__ __launch_bounds__(256) void k_ncat(const float* __restrict__ x,
                                              const unsigned* __restrict__ aggenc,
                                              float* __restrict__ ncat, int N) {
    int i = blockIdx.x * 256 + threadIdx.x;
    if (i >= N * 256) return;
    int n = i >> 8, c = i & 255;
    float v;
    if (c < 128) v = x[n * 128 + c];
    else {
        unsigned u = aggenc[n * 128 + c - 128];
        v = (u == ENC_NEGINF) ? 0.f : decf(u);
    }
    ncat[i] = v;
}

__global__ __launch_bounds__(256) void k_cat2(const float* __restrict__ outf,
                                              const float* __restrict__ incf,
                                              const int* __restrict__ rowcnt,
                                              const int* __restrict__ colcnt,
                                              float* __restrict__ cat2, int N) {
    int i = blockIdx.x * 256 + threadIdx.x;
    if (i >= N * 256) return;
    int n = i >> 8, c = i & 255;
    float v;
    if (c < 128) v = outf[n * 128 + c] / fmaxf((float)rowcnt[n], 1.f);
    else v = incf[n * 128 + c - 128] / fmaxf((float)colcnt[n], 1.f);
    cat2[i] = v;
}

__global__ __launch_bounds__(256) void k_final(const float* __restrict__ un,
                                               const float* __restrict__ eatt,
                                               float* __restrict__ dst, int NC) {
    int i = blockIdx.x * 256 + threadIdx.x;
    if (i >= NC) return;
    dst[i] = fmaxf(un[i], 0.f) * eatt[i];
}

// ---------------------------------------------------------------- host orchestration

extern "C" void kernel_launch(void* const* d_in, const int* in_sizes, int n_in,
                              void* d_out, int out_size, void* d_ws, size_t ws_size,
                              hipStream_t stream) {
    const float* node_feature = (const float*)d_in[0];
    const float* edge_feature = (const float*)d_in[1];
    const int* edges = (const int*)d_in[2];
    const float* desc = (const float*)d_in[3];
    const float* qW = (const float*)d_in[4];
    const float* qB = (const float*)d_in[5];
    const float* kW = (const float*)d_in[6];
    const float* kB = (const float*)d_in[7];
    const float* vW = (const float*)d_in[8];
    const float* vB = (const float*)d_in[9];
    const float* dW1 = (const float*)d_in[10];
    const float* dB1 = (const float*)d_in[11];
    const float* dW2 = (const float*)d_in[12];
    const float* dB2 = (const float*)d_in[13];
    const float* eW1 = (const float*)d_in[14];
    const float* eB1 = (const float*)d_in[15];
    const float* eW2 = (const float*)d_in[16];
    const float* eB2 = (const float*)d_in[17];
    const float* attW1 = (const float*)d_in[18];
    const float* attB1 = (const float*)d_in[19];
    const float* attW2 = (const float*)d_in[20];
    const float* attB2 = (const float*)d_in[21];
    const float* nW1 = (const float*)d_in[22];
    const float* nB1 = (const float*)d_in[23];
    const float* nW2 = (const float*)d_in[24];
    const float* nB2 = (const float*)d_in[25];
    const float* aW = (const float*)d_in[26];
    const float* aB = (const float*)d_in[27];

    const int N = in_sizes[0] / 128;
    const int E = in_sizes[2] / 2;
    const int L = 2;
    const int* row = edges;
    const int* col = edges + E;

    // workspace carve
    char* wsp = (char*)d_ws;
    auto alloc = [&](size_t bytes) {
        char* p = wsp;
        wsp += (bytes + 255) & ~(size_t)255;
        return p;
    };
    unsigned* hashK = (unsigned*)alloc((size_t)HS * 4);
    int* hashV = (int*)alloc((size_t)HS * 4);
    int* ridx = (int*)alloc((size_t)E * 4);
    int* rowcnt = (int*)alloc((size_t)N * 4);
    int* colcnt = (int*)alloc((size_t)N * 4);
    float* xq = (float*)alloc((size_t)N * 128 * 4);
    float* xv = (float*)alloc((size_t)N * 128 * 4);
    float* xa = (float*)alloc((size_t)N * 384 * 4);
    float* xb = (float*)alloc((size_t)N * 384 * 4);
    float* kbuf = (float*)alloc((size_t)E * 128 * 4);
    float* efbuf = (float*)alloc((size_t)E * 128 * 4);
    const int CH = 32000;
    float* h1c = (float*)alloc((size_t)CH * 384 * 4);
    unsigned* aggenc = (unsigned*)alloc((size_t)N * 128 * 4);
    float* ncat = (float*)alloc((size_t)N * 256 * 4);
    float* nh1 = (float*)alloc((size_t)N * 256 * 4);
    float* un = (float*)alloc((size_t)N * 128 * 4);
    float* outf = (float*)alloc((size_t)N * 128 * 4);
    float* incf = (float*)alloc((size_t)N * 128 * 4);
    float* cat2 = (float*)alloc((size_t)N * 256 * 4);
    float* eattb = (float*)alloc((size_t)N * 128 * 4);
    float* xbuf = (float*)alloc((size_t)N * 128 * 4);

    float* out_x = (float*)d_out;
    float* out_ef = out_x + (size_t)N * 128;
    float* out_prob = out_ef + (size_t)E * 128;

    // --- static (per-call) setup: reverse-edge map + degrees
    k_init_static<<<(HS + 255) / 256, 256, 0, stream>>>(hashK, hashV, rowcnt, colcnt, N);
    k_hash_insert<<<(E + 255) / 256, 256, 0, stream>>>(row, col, hashK, hashV, N, E);
    k_hash_lookup<<<(E + 255) / 256, 256, 0, stream>>>(row, col, hashK, hashV, ridx, rowcnt, colcnt, N, E);

    for (int l = 0; l < L; ++l) {
        const float* x_cur = (l == 0) ? node_feature : xbuf;
        const float* ef_cur = (l == 0) ? edge_feature : efbuf;
        const bool last = (l == L - 1);

        const float* qW_l = qW + (size_t)l * 128 * 128;
        const float* qB_l = qB + (size_t)l * 128;
        const float* kW_l = kW + (size_t)l * 128 * 128;
        const float* kB_l = kB + (size_t)l * 128;
        const float* vW_l = vW + (size_t)l * 128 * 128;
        const float* vB_l = vB + (size_t)l * 128;
        const float* dW1_l = dW1 + (size_t)l * 128;
        const float* dB1_l = dB1 + (size_t)l * 32;
        const float* dW2_l = dW2 + (size_t)l * 32;
        const float* dB2_l = dB2 + (size_t)l * 1;
        const float* eW1_l = eW1 + (size_t)l * 512 * 384;
        const float* eB1_l = eB1 + (size_t)l * 384;
        const float* eW2_l = eW2 + (size_t)l * 384 * 128;
        const float* eB2_l = eB2 + (size_t)l * 128;
        const float* attW1_l = attW1 + (size_t)l * 32 * 32;
        const float* attB1_l = attB1 + (size_t)l * 32;
        const float* attW2_l = attW2 + (size_t)l * 16 * 32;
        const float* attB2_l = attB2 + (size_t)l * 16;
        const float* nW1_l = nW1 + (size_t)l * 256 * 256;
        const float* nB1_l = nB1 + (size_t)l * 256;
        const float* nW2_l = nW2 + (size_t)l * 256 * 128;
        const float* nB2_l = nB2 + (size_t)l * 128;
        const float* aW_l = aW + (size_t)l * 256 * 128;
        const float* aB_l = aB + (size_t)l * 128;

        k_layer_init<<<(N * 128 + 255) / 256, 256, 0, stream>>>(aggenc, outf, incf, N * 128);

        int gy_n = (N + 63) / 64;
        // per-node precomputes
        k_gemm<0><<<dim3(2, gy_n), 256, 0, stream>>>(x_cur, qW_l, qB_l, xq, N, 128, 128, 128, 128, 128);
        k_gemm<0><<<dim3(2, gy_n), 256, 0, stream>>>(x_cur, vW_l, vB_l, xv, N, 128, 128, 128, 128, 128);
        k_gemm<0><<<dim3(6, gy_n), 256, 0, stream>>>(x_cur, eW1_l, nullptr, xa, N, 384, 128, 128, 384, 384);
        k_gemm<0><<<dim3(6, gy_n), 256, 0, stream>>>(x_cur, eW1_l + (size_t)384 * 384, nullptr, xb, N, 384, 128, 128, 384, 384);
        // per-edge k projection
        k_gemm<0><<<dim3(2, (E + 63) / 64), 256, 0, stream>>>(ef_cur, kW_l, kB_l, kbuf, E, 128, 128, 128, 128, 128);
        // attention + prob + segment-max
        k_attn<<<4096, 256, 0, stream>>>(xq, kbuf, xv, desc, row, col, attW1_l, attB1_l, attW2_l, attB2_l,
                                         dW1_l, dB1_l, dW2_l, dB2_l,
                                         out_prob + (size_t)l * E * 128, aggenc, E);
        // edge MLP in chunks
        for (int cb = 0; cb < E; cb += CH) {
            int mrows = (E - cb < CH) ? (E - cb) : CH;
            int gy = (mrows + 63) / 64;
            k_gemm_edge_h1<<<dim3(6, gy), 256, 0, stream>>>(ef_cur, ridx, eW1_l + (size_t)128 * 384, eB1_l,
                                                            xa, xb, row, col, h1c, cb, mrows);
            k_gemm_edge_u<<<dim3(2, gy), 256, 0, stream>>>(h1c, eW2_l, eB2_l, row, col, outf, incf,
                                                           last ? nullptr : efbuf,
                                                           last ? out_ef : nullptr, cb, mrows);
        }
        // node update
        k_ncat<<<(N * 256 + 255) / 256, 256, 0, stream>>>(x_cur, aggenc, ncat, N);
        k_gemm<1><<<dim3(4, gy_n), 256, 0, stream>>>(ncat, nW1_l, nB1_l, nh1, N, 256, 256, 256, 256, 256);
        k_gemm<0><<<dim3(2, gy_n), 256, 0, stream>>>(nh1, nW2_l, nB2_l, un, N, 128, 256, 256, 128, 128);
        k_cat2<<<(N * 256 + 255) / 256, 256, 0, stream>>>(outf, incf, rowcnt, colcnt, cat2, N);
        k_gemm<2><<<dim3(2, gy_n), 256, 0, stream>>>(cat2, aW_l, aB_l, eattb, N, 128, 256, 256, 128, 128);
        k_final<<<(N * 128 + 255) / 256, 256, 0, stream>>>(un, eattb, last ? out_x : xbuf, N * 128);
    }
}

// Round 3
// 2387.400 us; speedup vs baseline: 1.8824x; 1.5030x over previous
//
#include <hip/hip_runtime.h>
#include <math.h>

#define HS 524288
#define HSM (HS - 1)
#define ENC_NEGINF 0x007FFFFFu

__device__ __forceinline__ unsigned encf(float f) {
    unsigned b = __float_as_uint(f);
    return (b & 0x80000000u) ? ~b : (b | 0x80000000u);
}
__device__ __forceinline__ float decf(unsigned u) {
    return __uint_as_float((u & 0x80000000u) ? (u & 0x7FFFFFFFu) : ~u);
}

__device__ __forceinline__ unsigned short f2bf(float x) {
    unsigned u = __float_as_uint(x);
    unsigned r = u + 0x7FFFu + ((u >> 16) & 1u);
    return (unsigned short)(r >> 16);
}
__device__ __forceinline__ float bf2f(unsigned short h) {
    return __uint_as_float(((unsigned)h) << 16);
}

// ---------------------------------------------------------------- setup kernels

__global__ __launch_bounds__(256) void k_init_static(unsigned* hashK, int* hashV,
                                                     int* rowcnt, int* colcnt, int N) {
    int i = blockIdx.x * 256 + threadIdx.x;
    if (i < HS) { hashK[i] = 0xFFFFFFFFu; hashV[i] = 0x7FFFFFFF; }
    if (i < N) { rowcnt[i] = 0; colcnt[i] = 0; }
}

__global__ __launch_bounds__(256) void k_hash_insert(const int* __restrict__ row,
                                                     const int* __restrict__ col,
                                                     unsigned* hashK, int* hashV, int N, int E) {
    int e = blockIdx.x * 256 + threadIdx.x;
    if (e >= E) return;
    unsigned key = (unsigned)row[e] * (unsigned)N + (unsigned)col[e];
    unsigned h = (key * 2654435761u) >> 13; h &= HSM;
    while (true) {
        unsigned prev = atomicCAS(&hashK[h], 0xFFFFFFFFu, key);
        if (prev == 0xFFFFFFFFu || prev == key) { atomicMin(&hashV[h], e); break; }
        h = (h + 1) & HSM;
    }
}

__global__ __launch_bounds__(256) void k_hash_lookup(const int* __restrict__ row,
                                                     const int* __restrict__ col,
                                                     const unsigned* __restrict__ hashK,
                                                     const int* __restrict__ hashV,
                                                     int* __restrict__ ridx,
                                                     int* rowcnt, int* colcnt, int N, int E) {
    int e = blockIdx.x * 256 + threadIdx.x;
    if (e >= E) return;
    int r = row[e], c = col[e];
    unsigned rkey = (unsigned)c * (unsigned)N + (unsigned)r;
    unsigned h = (rkey * 2654435761u) >> 13; h &= HSM;
    int res = -1;
    while (true) {
        unsigned kk = hashK[h];
        if (kk == rkey) { res = hashV[h]; break; }
        if (kk == 0xFFFFFFFFu) break;
        h = (h + 1) & HSM;
    }
    ridx[e] = res;
    atomicAdd(&rowcnt[r], 1);
    atomicAdd(&colcnt[c], 1);
}

__global__ __launch_bounds__(256) void k_layer_init(unsigned* aggenc, float* outf, float* incf, int NC) {
    int i = blockIdx.x * 256 + threadIdx.x;
    if (i >= NC) return;
    aggenc[i] = ENC_NEGINF;
    outf[i] = 0.f;
    incf[i] = 0.f;
}

// Weight prep: src fp32 [K][Nn] row-major -> whi/wlo bf16 [Nn][K] (transposed + split)
__global__ __launch_bounds__(256) void k_prep_wt(const float* __restrict__ src,
                                                 unsigned short* __restrict__ whi,
                                                 unsigned short* __restrict__ wlo,
                                                 int K, int Nn) {
    int idx = blockIdx.x * 256 + threadIdx.x;
    if (idx >= K * Nn) return;
    int k = idx / Nn, n = idx - k * Nn;
    float v = src[idx];
    unsigned short h = f2bf(v);
    float hf = bf2f(h);
    unsigned short l = f2bf(v - hf);
    whi[(size_t)n * K + k] = h;
    wlo[(size_t)n * K + k] = l;
}

// ---------------------------------------------------------------- generic fp32 GEMM (node-side)
template <int ACT>
__global__ __launch_bounds__(256) void k_gemm(const float* __restrict__ A,
                                              const float* __restrict__ B,
                                              const float* __restrict__ bias,
                                              float* __restrict__ C,
                                              int M, int Nd, int K, int lda, int ldb, int ldc) {
    __shared__ float As[16][64];
    __shared__ float Bs[16][64];
    const int tid = threadIdx.x;
    const int bm = blockIdx.y * 64, bn = blockIdx.x * 64;
    const int tx = tid & 15, ty = tid >> 4;
    const int mload = tid >> 2, k4 = (tid & 3) << 2;
    const int kload = tid >> 4, n4 = (tid & 15) << 2;
    float acc[4][4] = {};
    const int gmload = bm + mload;
    const bool avalid = (gmload < M);
    const float* aptr = A + (size_t)(avalid ? gmload : (M - 1)) * lda + k4;
    const float* bptr = B + (size_t)kload * ldb + bn + n4;
    for (int kb = 0; kb < K; kb += 16) {
        float4 av = avalid ? *(const float4*)(aptr + kb) : make_float4(0.f, 0.f, 0.f, 0.f);
        As[k4 + 0][mload] = av.x; As[k4 + 1][mload] = av.y;
        As[k4 + 2][mload] = av.z; As[k4 + 3][mload] = av.w;
        *(float4*)&Bs[kload][n4] = *(const float4*)(bptr + (size_t)kb * ldb);
        __syncthreads();
#pragma unroll
        for (int k = 0; k < 16; ++k) {
            float4 a = *(const float4*)&As[k][ty << 2];
            float4 b = *(const float4*)&Bs[k][tx << 2];
            acc[0][0] += a.x * b.x; acc[0][1] += a.x * b.y; acc[0][2] += a.x * b.z; acc[0][3] += a.x * b.w;
            acc[1][0] += a.y * b.x; acc[1][1] += a.y * b.y; acc[1][2] += a.y * b.z; acc[1][3] += a.y * b.w;
            acc[2][0] += a.z * b.x; acc[2][1] += a.z * b.y; acc[2][2] += a.z * b.z; acc[2][3] += a.z * b.w;
            acc[3][0] += a.w * b.x; acc[3][1] += a.w * b.y; acc[3][2] += a.w * b.z; acc[3][3] += a.w * b.w;
        }
        __syncthreads();
    }
#pragma unroll
    for (int i = 0; i < 4; ++i) {
        int gm = bm + (ty << 2) + i;
        if (gm >= M) continue;
        float* crow = C + (size_t)gm * ldc;
#pragma unroll
        for (int j = 0; j < 4; ++j) {
            int gn = bn + (tx << 2) + j;
            float v = acc[i][j];
            if (bias) v += bias[gn];
            if (ACT == 1) v = fmaxf(v, 0.f);
            if (ACT == 2) v = 1.f / (1.f + __expf(-v));
            crow[gn] = v;
        }
    }
}

// ---------------------------------------------------------------- MFMA split-bf16 GEMM
// 128x128 tile, BK=32, 4 waves (2x2), each wave 64x64 via 16x16x32 bf16 MFMA.
// 3-term split: D += Ahi*Bhi + Alo*Bhi + Ahi*Blo  (error ~2^-17, fp32-equivalent).
// A is fp32 in memory, split on the fly during LDS staging. B is pre-split bf16 [N][K].
// MODE 0 (H1): A = [ef[e] | ef[ridx[e]]], K=256, epilogue relu(acc+eB1+xa[row]+xb[col]) -> h1c
// MODE 1 (U):  A = h1c, K=384, epilogue acc+eB2 -> atomics outf/incf + store (relu or raw)
// MODE 2 (K):  A = ef, K=128, epilogue acc+kB -> kbuf

#define LDP 40   // LDS row pitch in shorts (BK 32 + 8): 80B rows, 16B-aligned, ~2-way banks

using bfrag = __attribute__((ext_vector_type(8))) short;
using ffrag = __attribute__((ext_vector_type(4))) float;

template <int MODE, int KSTEPS>
__global__ __launch_bounds__(256) void k_mfma_gemm(const float* __restrict__ Asrc,
                                                   const int* __restrict__ ridx,
                                                   const unsigned short* __restrict__ Bhi,
                                                   const unsigned short* __restrict__ Blo,
                                                   const float* __restrict__ bias,
                                                   const float* __restrict__ xa,
                                                   const float* __restrict__ xb,
                                                   const int* __restrict__ rowArr,
                                                   const int* __restrict__ colArr,
                                                   float* __restrict__ outC,
                                                   float* __restrict__ outf,
                                                   float* __restrict__ incf,
                                                   int edgeBase, int Mrows, int reluOut) {
    constexpr int K = KSTEPS * 32;
    __shared__ unsigned short Ah[128 * LDP];
    __shared__ unsigned short Al[128 * LDP];
    __shared__ unsigned short Bh[128 * LDP];
    __shared__ unsigned short Bl[128 * LDP];

    const int tid = threadIdx.x;
    const int bm = blockIdx.y * 128;
    const int bx = blockIdx.x;

    // staging assignment: thread -> row r = tid>>1, k-half kh = (tid&1)*16
    const int sr = tid >> 1;
    const int kh = (tid & 1) * 16;

    // A row pointers
    const float* p0;
    const float* p1 = nullptr;
    {
        int rc = min(bm + sr, Mrows - 1);
        if (MODE == 0) {
            int e = edgeBase + rc;
            p0 = Asrc + (size_t)e * 128;
            int rv = ridx[e];
            p1 = (rv >= 0) ? (Asrc + (size_t)rv * 128) : nullptr;
        } else if (MODE == 1) {
            p0 = Asrc + (size_t)rc * 384;
        } else {
            p0 = Asrc + (size_t)rc * 128;
        }
    }
    // B row pointers
    const unsigned short* bhp = Bhi + (size_t)(bx * 128 + sr) * K + kh;
    const unsigned short* blp = Blo + (size_t)(bx * 128 + sr) * K + kh;

    const int wid = tid >> 6;
    const int lane = tid & 63;
    const int wr0 = (wid >> 1) * 64;
    const int wc0 = (wid & 1) * 64;
    const int lm = lane & 15;
    const int lk = (lane >> 4) * 8;

    ffrag acc[4][4];
#pragma unroll
    for (int i = 0; i < 4; ++i)
#pragma unroll
        for (int j = 0; j < 4; ++j)
            acc[i][j] = (ffrag){0.f, 0.f, 0.f, 0.f};

    unsigned short* AhW = &Ah[sr * LDP + kh];
    unsigned short* AlW = &Al[sr * LDP + kh];
    unsigned short* BhW = &Bh[sr * LDP + kh];
    unsigned short* BlW = &Bl[sr * LDP + kh];

    for (int ks = 0; ks < KSTEPS; ++ks) {
        const int kb = ks * 32;
        // ---- stage A (fp32 -> split bf16)
        const float* ap;
        if (MODE == 0) ap = (kb < 128) ? (p0 + kb) : (p1 ? p1 + (kb - 128) : nullptr);
        else ap = p0 + kb;
#pragma unroll
        for (int c = 0; c < 4; ++c) {
            float4 f = ap ? *(const float4*)(ap + kh + c * 4) : make_float4(0.f, 0.f, 0.f, 0.f);
            ushort4 h, l;
            h.x = f2bf(f.x); l.x = f2bf(f.x - bf2f(h.x));
            h.y = f2bf(f.y); l.y = f2bf(f.y - bf2f(h.y));
            h.z = f2bf(f.z); l.z = f2bf(f.z - bf2f(h.z));
            h.w = f2bf(f.w); l.w = f2bf(f.w - bf2f(h.w));
            *(ushort4*)(AhW + c * 4) = h;
            *(ushort4*)(AlW + c * 4) = l;
        }
        // ---- stage B (pre-split bf16, straight copy)
        {
            uint4 b0 = *(const uint4*)(bhp + kb);
            uint4 b1 = *(const uint4*)(bhp + kb + 8);
            uint4 c0 = *(const uint4*)(blp + kb);
            uint4 c1 = *(const uint4*)(blp + kb + 8);
            *(uint4*)(BhW) = b0; *(uint4*)(BhW + 8) = b1;
            *(uint4*)(BlW) = c0; *(uint4*)(BlW + 8) = c1;
        }
        __syncthreads();
        // ---- fragments + MFMA
        bfrag a_h[4], a_l[4], b_h[4], b_l[4];
#pragma unroll
        for (int mt = 0; mt < 4; ++mt) {
            int base = (wr0 + mt * 16 + lm) * LDP + lk;
            a_h[mt] = *(const bfrag*)&Ah[base];
            a_l[mt] = *(const bfrag*)&Al[base];
        }
#pragma unroll
        for (int nt = 0; nt < 4; ++nt) {
            int base = (wc0 + nt * 16 + lm) * LDP + lk;
            b_h[nt] = *(const bfrag*)&Bh[base];
            b_l[nt] = *(const bfrag*)&Bl[base];
        }
#pragma unroll
        for (int mt = 0; mt < 4; ++mt)
#pragma unroll
            for (int nt = 0; nt < 4; ++nt) {
                acc[mt][nt] = __builtin_amdgcn_mfma_f32_16x16x32_bf16(a_h[mt], b_h[nt], acc[mt][nt], 0, 0, 0);
                acc[mt][nt] = __builtin_amdgcn_mfma_f32_16x16x32_bf16(a_l[mt], b_h[nt], acc[mt][nt], 0, 0, 0);
                acc[mt][nt] = __builtin_amdgcn_mfma_f32_16x16x32_bf16(a_h[mt], b_l[nt], acc[mt][nt], 0, 0, 0);
            }
        __syncthreads();
    }

    // ---- epilogue. C/D layout: col = lane&15, row = (lane>>4)*4 + reg.
    float bv[4];
#pragma unroll
    for (int nt = 0; nt < 4; ++nt) bv[nt] = bias[bx * 128 + wc0 + nt * 16 + lm];

#pragma unroll
    for (int mt = 0; mt < 4; ++mt) {
#pragma unroll
        for (int i = 0; i < 4; ++i) {
            int grow = bm + wr0 + mt * 16 + (lane >> 4) * 4 + i;
            if (grow >= Mrows) continue;
            if (MODE == 0) {
                int e = edgeBase + grow;
                size_t re = (size_t)rowArr[e] * 384;
                size_t ce = (size_t)colArr[e] * 384;
                float* crow = outC + (size_t)grow * 384;
#pragma unroll
                for (int nt = 0; nt < 4; ++nt) {
                    int gcol = bx * 128 + wc0 + nt * 16 + lm;
                    float v = acc[mt][nt][i] + bv[nt] + xa[re + gcol] + xb[ce + gcol];
                    crow[gcol] = fmaxf(v, 0.f);
                }
            } else if (MODE == 1) {
                int e = edgeBase + grow;
                size_t re = (size_t)rowArr[e] * 128;
                size_t ce = (size_t)colArr[e] * 128;
                float* crow = outC + (size_t)e * 128;
#pragma unroll
                for (int nt = 0; nt < 4; ++nt) {
                    int gcol = wc0 + nt * 16 + lm;
                    float v = acc[mt][nt][i] + bv[nt];
                    atomicAdd(&outf[re + gcol], v);
                    atomicAdd(&incf[ce + gcol], v);
                    crow[gcol] = reluOut ? fmaxf(v, 0.f) : v;
                }
            } else {
                float* crow = outC + (size_t)grow * 128;
#pragma unroll
                for (int nt = 0; nt < 4; ++nt) {
                    int gcol = wc0 + nt * 16 + lm;
                    crow[gcol] = acc[mt][nt][i] + bv[nt];
                }
            }
        }
    }
}

// ---------------------------------------------------------------- attention kernel

__global__ __launch_bounds__(256) void k_attn(const float* __restrict__ xq,
                                              const float* __restrict__ kbuf,
                                              const float* __restrict__ xv,
                                              const float* __restrict__ desc,
                                              const int* __restrict__ row,
                                              const int* __restrict__ col,
                                              const float* __restrict__ attW1,
                                              const float* __restrict__ attB1,
                                              const float* __restrict__ attW2,
                                              const float* __restrict__ attB2,
                                              const float* __restrict__ dW1,
                                              const float* __restrict__ dB1,
                                              const float* __restrict__ dW2,
                                              const float* __restrict__ dB2,
                                              float* __restrict__ prob_out,
                                              unsigned* __restrict__ aggenc, int E) {
    __shared__ float w1t[32 * 36];
    __shared__ float w2t[32 * 18];
    __shared__ float sdw1[128];
    __shared__ float sQ[4][128];
    __shared__ float sK[4][128];
    __shared__ float sV[4][128];
    __shared__ float sP[4][128];
    for (int i = threadIdx.x; i < 1024; i += 256) {
        int o = i >> 5, c = i & 31;
        w1t[c * 36 + o] = attW1[i];
    }
    for (int i = threadIdx.x; i < 512; i += 256) {
        int o = i >> 5, c = i & 31;
        w2t[c * 18 + o] = attW2[i];
    }
    for (int i = threadIdx.x; i < 128; i += 256) sdw1[i] = dW1[i];
    __syncthreads();

    const int wv = threadIdx.x >> 6;
    const int lane = threadIdx.x & 63;
    const int hd = lane & 7;
    const int og = lane >> 3;
    const int c32 = lane & 31;
    const int nw = (gridDim.x * 256) >> 6;
    const int wid = (blockIdx.x * 256 + threadIdx.x) >> 6;

    float* myQ = sQ[wv];
    float* myK = sK[wv];
    float* myV = sV[wv];
    float* myP = sP[wv];

    const float b1_0 = attB1[og * 4 + 0], b1_1 = attB1[og * 4 + 1];
    const float b1_2 = attB1[og * 4 + 2], b1_3 = attB1[og * 4 + 3];
    const float b2_0 = attB2[og * 2 + 0], b2_1 = attB2[og * 2 + 1];
    const float db2v = dB2[0];
    const float dw2v = dW2[c32];
    const float db1v = dB1[c32];

    for (int e0 = wid; e0 < E; e0 += nw) {
        const int e = __builtin_amdgcn_readfirstlane(e0);
        const int r = row[e], cl = col[e];
        float2 qv = *(const float2*)(xq + (size_t)r * 128 + lane * 2);
        float2 kv = *(const float2*)(kbuf + (size_t)e * 128 + lane * 2);
        float2 vv = *(const float2*)(xv + (size_t)cl * 128 + lane * 2);
        *(float2*)(myQ + lane * 2) = qv;
        *(float2*)(myK + lane * 2) = kv;
        *(float2*)(myV + lane * 2) = vv;
        __builtin_amdgcn_wave_barrier();

        float dx = desc[r * 8 + 0] - desc[cl * 8 + 0];
        float dy = desc[r * 8 + 1] - desc[cl * 8 + 1];
        float dz = desc[r * 8 + 2] - desc[cl * 8 + 2];
        float dist = sqrtf(dx * dx + dy * dy + dz * dz);
        float t = db1v + dx * sdw1[c32] + dy * sdw1[32 + c32] + dz * sdw1[64 + c32] + dist * sdw1[96 + c32];
        t = fmaxf(t, 0.f) * dw2v;
        t += __shfl_xor(t, 1, 64); t += __shfl_xor(t, 2, 64); t += __shfl_xor(t, 4, 64);
        t += __shfl_xor(t, 8, 64); t += __shfl_xor(t, 16, 64);
        float dm = 1.f / (1.f + __expf(-(t + db2v)));

        float h0 = b1_0, h1v = b1_1, h2 = b1_2, h3 = b1_3;
#pragma unroll
        for (int ci = 0; ci < 16; ++ci) {
            float hv = myQ[ci * 8 + hd];
            const float4 w = *(const float4*)&w1t[ci * 36 + og * 4];
            h0 += hv * w.x; h1v += hv * w.y; h2 += hv * w.z; h3 += hv * w.w;
        }
#pragma unroll
        for (int ci = 0; ci < 16; ++ci) {
            float hv = myK[ci * 8 + hd];
            const float4 w = *(const float4*)&w1t[(16 + ci) * 36 + og * 4];
            h0 += hv * w.x; h1v += hv * w.y; h2 += hv * w.z; h3 += hv * w.w;
        }
        float hreg[4];
        hreg[0] = fmaxf(h0, 0.f); hreg[1] = fmaxf(h1v, 0.f);
        hreg[2] = fmaxf(h2, 0.f); hreg[3] = fmaxf(h3, 0.f);

        float a0 = b2_0, a1 = b2_1;
#pragma unroll
        for (int c = 0; c < 32; ++c) {
            int src = (c >> 2) * 8 + hd;
            float hv = __shfl(hreg[c & 3], src, 64);
            const float2 w = *(const float2*)&w2t[c * 18 + og * 2];
            a0 += hv * w.x; a1 += hv * w.y;
        }
        float sc = dm * 0.25f;
        a0 *= sc; a1 *= sc;

        float mx = fmaxf(a0, a1);
        mx = fmaxf(mx, __shfl_xor(mx, 8, 64));
        mx = fmaxf(mx, __shfl_xor(mx, 16, 64));
        mx = fmaxf(mx, __shfl_xor(mx, 32, 64));
        float e0v = __expf(a0 - mx), e1v = __expf(a1 - mx);
        float s = e0v + e1v;
        s += __shfl_xor(s, 8, 64); s += __shfl_xor(s, 16, 64); s += __shfl_xor(s, 32, 64);
        float inv = 1.f / s;
        float p0 = e0v * inv, p1 = e1v * inv;

        myP[og * 16 + hd] = p0;
        myP[og * 16 + hd + 8] = p1;

        float v0 = myV[og * 16 + hd] * p0;
        float v1 = myV[og * 16 + hd + 8] * p1;
        unsigned* ab = aggenc + (size_t)r * 128 + og * 16 + hd;
        atomicMax(ab, encf(v0));
        atomicMax(ab + 8, encf(v1));

        __builtin_amdgcn_wave_barrier();
        *(float2*)(prob_out + (size_t)e * 128 + lane * 2) = *(const float2*)(myP + lane * 2);
    }
}

// ---------------------------------------------------------------- small elementwise kernels

__global__ __launch_bounds__(256) void k_ncat(const float* __restrict__ x,
                                              const unsigned* __restrict__ aggenc,
                                              float* __restrict__ ncat, int N) {
    int i = blockIdx.x * 256 + threadIdx.x;
    if (i >= N * 256) return;
    int n = i >> 8, c = i & 255;
    float v;
    if (c < 128) v = x[n * 128 + c];
    else {
        unsigned u = aggenc[n * 128 + c - 128];
        v = (u == ENC_NEGINF) ? 0.f : decf(u);
    }
    ncat[i] = v;
}

__global__ __launch_bounds__(256) void k_cat2(const float* __restrict__ outf,
                                              const float* __restrict__ incf,
                                              const int* __restrict__ rowcnt,
                                              const int* __restrict__ colcnt,
                                              float* __restrict__ cat2, int N) {
    int i = blockIdx.x * 256 + threadIdx.x;
    if (i >= N * 256) return;
    int n = i >> 8, c = i & 255;
    float v;
    if (c < 128) v = outf[n * 128 + c] / fmaxf((float)rowcnt[n], 1.f);
    else v = incf[n * 128 + c - 128] / fmaxf((float)colcnt[n], 1.f);
    cat2[i] = v;
}

__global__ __launch_bounds__(256) void k_final(const float* __restrict__ un,
                                               const float* __restrict__ eatt,
                                               float* __restrict__ dst, int NC) {
    int i = blockIdx.x * 256 + threadIdx.x;
    if (i >= NC) return;
    dst[i] = fmaxf(un[i], 0.f) * eatt[i];
}

// ---------------------------------------------------------------- host orchestration

extern "C" void kernel_launch(void* const* d_in, const int* in_sizes, int n_in,
                              void* d_out, int out_size, void* d_ws, size_t ws_size,
                              hipStream_t stream) {
    const float* node_feature = (const float*)d_in[0];
    const float* edge_feature = (const float*)d_in[1];
    const int* edges = (const int*)d_in[2];
    const float* desc = (const float*)d_in[3];
    const float* qW = (const float*)d_in[4];
    const float* qB = (const float*)d_in[5];
    const float* kW = (const float*)d_in[6];
    const float* kB = (const float*)d_in[7];
    const float* vW = (const float*)d_in[8];
    const float* vB = (const float*)d_in[9];
    const float* dW1 = (const float*)d_in[10];
    const float* dB1 = (const float*)d_in[11];
    const float* dW2 = (const float*)d_in[12];
    const float* dB2 = (const float*)d_in[13];
    const float* eW1 = (const float*)d_in[14];
    const float* eB1 = (const float*)d_in[15];
    const float* eW2 = (const float*)d_in[16];
    const float* eB2 = (const float*)d_in[17];
    const float* attW1 = (const float*)d_in[18];
    const float* attB1 = (const float*)d_in[19];
    const float* attW2 = (const float*)d_in[20];
    const float* attB2 = (const float*)d_in[21];
    const float* nW1 = (const float*)d_in[22];
    const float* nB1 = (const float*)d_in[23];
    const float* nW2 = (const float*)d_in[24];
    const float* nB2 = (const float*)d_in[25];
    const float* aW = (const float*)d_in[26];
    const float* aB = (const float*)d_in[27];

    const int N = in_sizes[0] / 128;
    const int E = in_sizes[2] / 2;
    const int L = 2;
    const int* row = edges;
    const int* col = edges + E;

    char* wsp = (char*)d_ws;
    auto alloc = [&](size_t bytes) {
        char* p = wsp;
        wsp += (bytes + 255) & ~(size_t)255;
        return p;
    };
    unsigned* hashK = (unsigned*)alloc((size_t)HS * 4);
    int* hashV = (int*)alloc((size_t)HS * 4);
    int* ridx = (int*)alloc((size_t)E * 4);
    int* rowcnt = (int*)alloc((size_t)N * 4);
    int* colcnt = (int*)alloc((size_t)N * 4);
    float* xq = (float*)alloc((size_t)N * 128 * 4);
    float* xv = (float*)alloc((size_t)N * 128 * 4);
    float* xa = (float*)alloc((size_t)N * 384 * 4);
    float* xb = (float*)alloc((size_t)N * 384 * 4);
    float* kbuf = (float*)alloc((size_t)E * 128 * 4);
    float* efbuf = (float*)alloc((size_t)E * 128 * 4);
    const int CH = 32000;
    float* h1c = (float*)alloc((size_t)CH * 384 * 4);
    unsigned* aggenc = (unsigned*)alloc((size_t)N * 128 * 4);
    float* ncat = (float*)alloc((size_t)N * 256 * 4);
    float* nh1 = (float*)alloc((size_t)N * 256 * 4);
    float* un = (float*)alloc((size_t)N * 128 * 4);
    float* outf = (float*)alloc((size_t)N * 128 * 4);
    float* incf = (float*)alloc((size_t)N * 128 * 4);
    float* cat2 = (float*)alloc((size_t)N * 256 * 4);
    float* eattb = (float*)alloc((size_t)N * 128 * 4);
    float* xbuf = (float*)alloc((size_t)N * 128 * 4);
    unsigned short* wt1_hi = (unsigned short*)alloc((size_t)384 * 256 * 2);
    unsigned short* wt1_lo = (unsigned short*)alloc((size_t)384 * 256 * 2);
    unsigned short* wt2_hi = (unsigned short*)alloc((size_t)128 * 384 * 2);
    unsigned short* wt2_lo = (unsigned short*)alloc((size_t)128 * 384 * 2);
    unsigned short* wtk_hi = (unsigned short*)alloc((size_t)128 * 128 * 2);
    unsigned short* wtk_lo = (unsigned short*)alloc((size_t)128 * 128 * 2);

    float* out_x = (float*)d_out;
    float* out_ef = out_x + (size_t)N * 128;
    float* out_prob = out_ef + (size_t)E * 128;

    k_init_static<<<(HS + 255) / 256, 256, 0, stream>>>(hashK, hashV, rowcnt, colcnt, N);
    k_hash_insert<<<(E + 255) / 256, 256, 0, stream>>>(row, col, hashK, hashV, N, E);
    k_hash_lookup<<<(E + 255) / 256, 256, 0, stream>>>(row, col, hashK, hashV, ridx, rowcnt, colcnt, N, E);

    for (int l = 0; l < L; ++l) {
        const float* x_cur = (l == 0) ? node_feature : xbuf;
        const float* ef_cur = (l == 0) ? edge_feature : efbuf;
        const bool last = (l == L - 1);

        const float* qW_l = qW + (size_t)l * 128 * 128;
        const float* qB_l = qB + (size_t)l * 128;
        const float* kW_l = kW + (size_t)l * 128 * 128;
        const float* kB_l = kB + (size_t)l * 128;
        const float* vW_l = vW + (size_t)l * 128 * 128;
        const float* vB_l = vB + (size_t)l * 128;
        const float* dW1_l = dW1 + (size_t)l * 128;
        const float* dB1_l = dB1 + (size_t)l * 32;
        const float* dW2_l = dW2 + (size_t)l * 32;
        const float* dB2_l = dB2 + (size_t)l * 1;
        const float* eW1_l = eW1 + (size_t)l * 512 * 384;
        const float* eB1_l = eB1 + (size_t)l * 384;
        const float* eW2_l = eW2 + (size_t)l * 384 * 128;
        const float* eB2_l = eB2 + (size_t)l * 128;
        const float* attW1_l = attW1 + (size_t)l * 32 * 32;
        const float* attB1_l = attB1 + (size_t)l * 32;
        const float* attW2_l = attW2 + (size_t)l * 16 * 32;
        const float* attB2_l = attB2 + (size_t)l * 16;
        const float* nW1_l = nW1 + (size_t)l * 256 * 256;
        const float* nB1_l = nB1 + (size_t)l * 256;
        const float* nW2_l = nW2 + (size_t)l * 256 * 128;
        const float* nB2_l = nB2 + (size_t)l * 128;
        const float* aW_l = aW + (size_t)l * 256 * 128;
        const float* aB_l = aB + (size_t)l * 128;

        // weight prep (transpose + bf16 split)
        k_prep_wt<<<(256 * 384 + 255) / 256, 256, 0, stream>>>(eW1_l + (size_t)128 * 384, wt1_hi, wt1_lo, 256, 384);
        k_prep_wt<<<(384 * 128 + 255) / 256, 256, 0, stream>>>(eW2_l, wt2_hi, wt2_lo, 384, 128);
        k_prep_wt<<<(128 * 128 + 255) / 256, 256, 0, stream>>>(kW_l, wtk_hi, wtk_lo, 128, 128);

        k_layer_init<<<(N * 128 + 255) / 256, 256, 0, stream>>>(aggenc, outf, incf, N * 128);

        int gy_n = (N + 63) / 64;
        // per-node precomputes (fp32)
        k_gemm<0><<<dim3(2, gy_n), 256, 0, stream>>>(x_cur, qW_l, qB_l, xq, N, 128, 128, 128, 128, 128);
        k_gemm<0><<<dim3(2, gy_n), 256, 0, stream>>>(x_cur, vW_l, vB_l, xv, N, 128, 128, 128, 128, 128);
        k_gemm<0><<<dim3(6, gy_n), 256, 0, stream>>>(x_cur, eW1_l, nullptr, xa, N, 384, 128, 128, 384, 384);
        k_gemm<0><<<dim3(6, gy_n), 256, 0, stream>>>(x_cur, eW1_l + (size_t)384 * 384, nullptr, xb, N, 384, 128, 128, 384, 384);
        // per-edge k projection (MFMA)
        k_mfma_gemm<2, 4><<<dim3(1, (E + 127) / 128), 256, 0, stream>>>(
            ef_cur, nullptr, wtk_hi, wtk_lo, kB_l, nullptr, nullptr, nullptr, nullptr,
            kbuf, nullptr, nullptr, 0, E, 0);
        // attention + prob + segment-max
        k_attn<<<4096, 256, 0, stream>>>(xq, kbuf, xv, desc, row, col, attW1_l, attB1_l, attW2_l, attB2_l,
                                         dW1_l, dB1_l, dW2_l, dB2_l,
                                         out_prob + (size_t)l * E * 128, aggenc, E);
        // edge MLP in chunks (MFMA)
        for (int cb = 0; cb < E; cb += CH) {
            int mrows = (E - cb < CH) ? (E - cb) : CH;
            int gy = (mrows + 127) / 128;
            k_mfma_gemm<0, 8><<<dim3(3, gy), 256, 0, stream>>>(
                ef_cur, ridx, wt1_hi, wt1_lo, eB1_l, xa, xb, row, col,
                h1c, nullptr, nullptr, cb, mrows, 0);
            k_mfma_gemm<1, 12><<<dim3(1, gy), 256, 0, stream>>>(
                h1c, nullptr, wt2_hi, wt2_lo, eB2_l, nullptr, nullptr, row, col,
                last ? out_ef : efbuf, outf, incf, cb, mrows, last ? 0 : 1);
        }
        // node update
        k_ncat<<<(N * 256 + 255) / 256, 256, 0, stream>>>(x_cur, aggenc, ncat, N);
        k_gemm<1><<<dim3(4, gy_n), 256, 0, stream>>>(ncat, nW1_l, nB1_l, nh1, N, 256, 256, 256, 256, 256);
        k_gemm<0><<<dim3(2, gy_n), 256, 0, stream>>>(nh1, nW2_l, nB2_l, un, N, 128, 256, 256, 128, 128);
        k_cat2<<<(N * 256 + 255) / 256, 256, 0, stream>>>(outf, incf, rowcnt, colcnt, cat2, N);
        k_gemm<2><<<dim3(2, gy_n), 256, 0, stream>>>(cat2, aW_l, aB_l, eattb, N, 128, 256, 256, 128, 128);
        k_final<<<(N * 128 + 255) / 256, 256, 0, stream>>>(un, eattb, last ? out_x : xbuf, N * 128);
    }
}